// Round 1
// baseline (2314.170 us; speedup 1.0000x reference)
//
#include <hip/hip_runtime.h>
#include <hip/hip_bf16.h>
#include <math.h>

typedef __bf16 bf16;
typedef __bf16 bf16x8 __attribute__((ext_vector_type(8)));
typedef float f32x4 __attribute__((ext_vector_type(4)));

#define MFMA(a, b, c) __builtin_amdgcn_mfma_f32_16x16x32_bf16((a), (b), (c), 0, 0, 0)

static __device__ __forceinline__ bf16x8 bzero8() {
  bf16x8 v;
#pragma unroll
  for (int i = 0; i < 8; ++i) v[i] = (bf16)0.0f;
  return v;
}

// ---------- W (K x N fp32, row-major) -> Wt (N x K bf16, row-major) ----------
__global__ void k_transpose_cvt(const float* __restrict__ W, bf16* __restrict__ Wt,
                                int K, int N) {
  __shared__ float tile[32][33];
  int k0 = blockIdx.x * 32, n0 = blockIdx.y * 32;
  int tx = threadIdx.x & 31, ty = threadIdx.x >> 5;
  for (int i = ty; i < 32; i += 8)
    tile[i][tx] = W[(size_t)(k0 + i) * N + (n0 + tx)];
  __syncthreads();
  for (int i = ty; i < 32; i += 8)
    Wt[(size_t)(n0 + i) * K + (k0 + tx)] = (bf16)tile[tx][i];
}

// ---------- fp32 -> bf16 flat convert ----------
__global__ void k_cvt(const float* __restrict__ in, bf16* __restrict__ out, int n) {
  int i = blockIdx.x * 256 + threadIdx.x;
  if (i < n) out[i] = (bf16)in[i];
}

// ---------- LayerNorm over D=1024, one block per row, bf16 out ----------
__global__ void k_layernorm(const float* __restrict__ x, const float* __restrict__ g,
                            const float* __restrict__ b, bf16* __restrict__ out) {
  int row = blockIdx.x;
  float4 v = ((const float4*)(x + (size_t)row * 1024))[threadIdx.x];
  float s = v.x + v.y + v.z + v.w;
  float ss = v.x * v.x + v.y * v.y + v.z * v.z + v.w * v.w;
#pragma unroll
  for (int off = 1; off < 64; off <<= 1) {
    s += __shfl_xor(s, off);
    ss += __shfl_xor(ss, off);
  }
  __shared__ float sm[4], sm2[4];
  int w = threadIdx.x >> 6;
  if ((threadIdx.x & 63) == 0) { sm[w] = s; sm2[w] = ss; }
  __syncthreads();
  s = sm[0] + sm[1] + sm[2] + sm[3];
  ss = sm2[0] + sm2[1] + sm2[2] + sm2[3];
  float mu = s * (1.0f / 1024.0f);
  float var = ss * (1.0f / 1024.0f) - mu * mu;
  float rs = rsqrtf(var + 1e-5f);
  float4 gg = ((const float4*)g)[threadIdx.x];
  float4 bb = ((const float4*)b)[threadIdx.x];
  bf16* o = out + (size_t)row * 1024 + threadIdx.x * 4;
  o[0] = (bf16)((v.x - mu) * rs * gg.x + bb.x);
  o[1] = (bf16)((v.y - mu) * rs * gg.y + bb.y);
  o[2] = (bf16)((v.z - mu) * rs * gg.z + bb.z);
  o[3] = (bf16)((v.w - mu) * rs * gg.w + bb.w);
}

// ---------- GEMM: C[M,N] = A[M,K] @ Bt[N,K]^T  (bf16 in, fp32 acc) ----------
// EPI 0: store bf16 C.  EPI 1: store fp32 C = acc + bias[col] + res[row,col].
template <int EPI>
__global__ void k_gemm_bt(const bf16* __restrict__ A, const bf16* __restrict__ Bt,
                          const float* __restrict__ bias, const float* __restrict__ res,
                          void* __restrict__ Cp, int M, int N, int K) {
  __shared__ __attribute__((aligned(16))) bf16 As[128][40];
  __shared__ __attribute__((aligned(16))) bf16 Bs[128][40];
  int m0 = blockIdx.x * 128, n0 = blockIdx.y * 128;
  int tid = threadIdx.x, lane = tid & 63, wave = tid >> 6;
  int wm = (wave >> 1) * 64, wn = (wave & 1) * 64;
  int quad = lane >> 4, l15 = lane & 15;
  f32x4 acc[4][4];
#pragma unroll
  for (int i = 0; i < 4; ++i)
#pragma unroll
    for (int j = 0; j < 4; ++j)
#pragma unroll
      for (int r = 0; r < 4; ++r) acc[i][j][r] = 0.0f;
  int srow = tid >> 2, scol = (tid & 3) * 8;
  for (int k0 = 0; k0 < K; k0 += 32) {
#pragma unroll
    for (int rr = 0; rr < 2; ++rr) {
      int r = srow + rr * 64;
      int gm = m0 + r;
      bf16x8 av = bzero8();
      if (gm < M) av = *(const bf16x8*)(A + (size_t)gm * K + k0 + scol);
      *(bf16x8*)(&As[r][scol]) = av;
      int gn = n0 + r;
      bf16x8 bv = bzero8();
      if (gn < N) bv = *(const bf16x8*)(Bt + (size_t)gn * K + k0 + scol);
      *(bf16x8*)(&Bs[r][scol]) = bv;
    }
    __syncthreads();
    bf16x8 af[4], bfr[4];
#pragma unroll
    for (int i = 0; i < 4; ++i) af[i] = *(const bf16x8*)(&As[wm + i * 16 + l15][quad * 8]);
#pragma unroll
    for (int i = 0; i < 4; ++i) bfr[i] = *(const bf16x8*)(&Bs[wn + i * 16 + l15][quad * 8]);
#pragma unroll
    for (int mi = 0; mi < 4; ++mi)
#pragma unroll
      for (int ni = 0; ni < 4; ++ni)
        acc[mi][ni] = MFMA(af[mi], bfr[ni], acc[mi][ni]);
    __syncthreads();
  }
#pragma unroll
  for (int mi = 0; mi < 4; ++mi) {
#pragma unroll
    for (int r = 0; r < 4; ++r) {
      int row = m0 + wm + mi * 16 + quad * 4 + r;
      if (row >= M) continue;
#pragma unroll
      for (int ni = 0; ni < 4; ++ni) {
        int col = n0 + wn + ni * 16 + l15;
        float v = acc[mi][ni][r];
        if (EPI == 0) {
          ((bf16*)Cp)[(size_t)row * N + col] = (bf16)v;
        } else {
          ((float*)Cp)[(size_t)row * N + col] =
              v + bias[col] + res[(size_t)row * N + col];
        }
      }
    }
  }
}

// ---------- GEMM + GeGLU: Hg[M,4096] = (A@W1t[:4096]+b1u) * gelu(A@W1t[4096:]+b1g) ----------
__global__ void k_gemm_geglu(const bf16* __restrict__ A, const bf16* __restrict__ W1t,
                             const float* __restrict__ b1, bf16* __restrict__ Hg,
                             int M, int K) {
  __shared__ __attribute__((aligned(16))) bf16 As[128][40];
  __shared__ __attribute__((aligned(16))) bf16 Bu[128][40];
  __shared__ __attribute__((aligned(16))) bf16 Bg[128][40];
  const int N = 4096;
  int m0 = blockIdx.x * 128, n0 = blockIdx.y * 128;
  int tid = threadIdx.x, lane = tid & 63, wave = tid >> 6;
  int wm = (wave >> 1) * 64, wn = (wave & 1) * 64;
  int quad = lane >> 4, l15 = lane & 15;
  f32x4 accu[4][4], accg[4][4];
#pragma unroll
  for (int i = 0; i < 4; ++i)
#pragma unroll
    for (int j = 0; j < 4; ++j)
#pragma unroll
      for (int r = 0; r < 4; ++r) { accu[i][j][r] = 0.0f; accg[i][j][r] = 0.0f; }
  int srow = tid >> 2, scol = (tid & 3) * 8;
  for (int k0 = 0; k0 < K; k0 += 32) {
#pragma unroll
    for (int rr = 0; rr < 2; ++rr) {
      int r = srow + rr * 64;
      *(bf16x8*)(&As[r][scol]) = *(const bf16x8*)(A + (size_t)(m0 + r) * K + k0 + scol);
      *(bf16x8*)(&Bu[r][scol]) = *(const bf16x8*)(W1t + (size_t)(n0 + r) * K + k0 + scol);
      *(bf16x8*)(&Bg[r][scol]) = *(const bf16x8*)(W1t + (size_t)(n0 + r + 4096) * K + k0 + scol);
    }
    __syncthreads();
    bf16x8 af[4], bu[4], bg[4];
#pragma unroll
    for (int i = 0; i < 4; ++i) af[i] = *(const bf16x8*)(&As[wm + i * 16 + l15][quad * 8]);
#pragma unroll
    for (int i = 0; i < 4; ++i) bu[i] = *(const bf16x8*)(&Bu[wn + i * 16 + l15][quad * 8]);
#pragma unroll
    for (int i = 0; i < 4; ++i) bg[i] = *(const bf16x8*)(&Bg[wn + i * 16 + l15][quad * 8]);
#pragma unroll
    for (int mi = 0; mi < 4; ++mi)
#pragma unroll
      for (int ni = 0; ni < 4; ++ni) {
        accu[mi][ni] = MFMA(af[mi], bu[ni], accu[mi][ni]);
        accg[mi][ni] = MFMA(af[mi], bg[ni], accg[mi][ni]);
      }
    __syncthreads();
  }
#pragma unroll
  for (int mi = 0; mi < 4; ++mi)
#pragma unroll
    for (int r = 0; r < 4; ++r) {
      int row = m0 + wm + mi * 16 + quad * 4 + r;
#pragma unroll
      for (int ni = 0; ni < 4; ++ni) {
        int col = n0 + wn + ni * 16 + l15;
        float u = accu[mi][ni][r] + b1[col];
        float g = accg[mi][ni][r] + b1[col + 4096];
        float ge = 0.5f * g * (1.0f + erff(g * 0.70710678118654752f));
        Hg[(size_t)row * N + col] = (bf16)(u * ge);
      }
    }
}

// ---------- Flash attention: 64 q-rows per block, 64-key chunks ----------
// Q: (B*Sq,1024) bf16, head h at col h*64. K/V: (B*kvrows,1024) bf16. O: bf16.
__global__ void k_flash(const bf16* __restrict__ Q, const bf16* __restrict__ Kb,
                        const bf16* __restrict__ Vb, bf16* __restrict__ O,
                        int Sq, int Sk, int kvrows) {
  __shared__ __attribute__((aligned(16))) bf16 Qs[64][72];
  __shared__ __attribute__((aligned(16))) bf16 Ks[64][72];
  __shared__ __attribute__((aligned(16))) bf16 Vt[64][72];
  __shared__ __attribute__((aligned(16))) bf16 Ps[4][16][72];
  int qt = blockIdx.x, h = blockIdx.y, b = blockIdx.z;
  int tid = threadIdx.x, lane = tid & 63, wave = tid >> 6;
  int quad = lane >> 4, l15 = lane & 15;
  {
    int r = tid >> 2, c0 = (tid & 3) * 16;
    const bf16* src = Q + (size_t)(b * Sq + qt * 64 + r) * 1024 + h * 64 + c0;
    *(bf16x8*)(&Qs[r][c0]) = *(const bf16x8*)(src);
    *(bf16x8*)(&Qs[r][c0 + 8]) = *(const bf16x8*)(src + 8);
  }
  float m_r[4], l_r[4];
  f32x4 acc_o[4];
#pragma unroll
  for (int r = 0; r < 4; ++r) { m_r[r] = -1e30f; l_r[r] = 0.0f; }
#pragma unroll
  for (int ni = 0; ni < 4; ++ni)
#pragma unroll
    for (int r = 0; r < 4; ++r) acc_o[ni][r] = 0.0f;

  for (int k0 = 0; k0 < Sk; k0 += 64) {
    {
      int r = tid >> 2, c0 = (tid & 3) * 16;
      int krow = k0 + r;
      bf16x8 k1 = bzero8(), k2 = bzero8(), v1 = bzero8(), v2 = bzero8();
      if (krow < Sk) {
        const bf16* ks = Kb + (size_t)(b * kvrows + krow) * 1024 + h * 64 + c0;
        k1 = *(const bf16x8*)ks;
        k2 = *(const bf16x8*)(ks + 8);
        const bf16* vs = Vb + (size_t)(b * kvrows + krow) * 1024 + h * 64 + c0;
        v1 = *(const bf16x8*)vs;
        v2 = *(const bf16x8*)(vs + 8);
      }
      *(bf16x8*)(&Ks[r][c0]) = k1;
      *(bf16x8*)(&Ks[r][c0 + 8]) = k2;
#pragma unroll
      for (int j = 0; j < 8; ++j) { Vt[c0 + j][r] = v1[j]; Vt[c0 + 8 + j][r] = v2[j]; }
    }
    __syncthreads();

    // S = Q(16 rows of this wave) @ K^T  -> sacc[ni][r] = S[quad*4+r][ni*16+l15]
    f32x4 sacc[4];
#pragma unroll
    for (int ni = 0; ni < 4; ++ni)
#pragma unroll
      for (int r = 0; r < 4; ++r) sacc[ni][r] = 0.0f;
#pragma unroll
    for (int ks = 0; ks < 2; ++ks) {
      bf16x8 aq = *(const bf16x8*)(&Qs[wave * 16 + l15][ks * 32 + quad * 8]);
#pragma unroll
      for (int ni = 0; ni < 4; ++ni) {
        bf16x8 bk = *(const bf16x8*)(&Ks[ni * 16 + l15][ks * 32 + quad * 8]);
        sacc[ni] = MFMA(aq, bk, sacc[ni]);
      }
    }
    float s_v[4][4];
#pragma unroll
    for (int ni = 0; ni < 4; ++ni)
#pragma unroll
      for (int r = 0; r < 4; ++r) {
        float sv = sacc[ni][r] * 0.125f;  // DH^-0.5
        if (k0 + ni * 16 + l15 >= Sk) sv = -1e30f;
        s_v[ni][r] = sv;
      }
    float alpha[4];
#pragma unroll
    for (int r = 0; r < 4; ++r) {
      float v = fmaxf(fmaxf(s_v[0][r], s_v[1][r]), fmaxf(s_v[2][r], s_v[3][r]));
#pragma unroll
      for (int off = 1; off < 16; off <<= 1) v = fmaxf(v, __shfl_xor(v, off));
      float mn = fmaxf(m_r[r], v);
      alpha[r] = __expf(m_r[r] - mn);
      m_r[r] = mn;
    }
    float p_v[4][4];
#pragma unroll
    for (int ni = 0; ni < 4; ++ni)
#pragma unroll
      for (int r = 0; r < 4; ++r) p_v[ni][r] = __expf(s_v[ni][r] - m_r[r]);
#pragma unroll
    for (int r = 0; r < 4; ++r) {
      float v = p_v[0][r] + p_v[1][r] + p_v[2][r] + p_v[3][r];
#pragma unroll
      for (int off = 1; off < 16; off <<= 1) v += __shfl_xor(v, off);
      l_r[r] = l_r[r] * alpha[r] + v;
    }
#pragma unroll
    for (int ni = 0; ni < 4; ++ni)
#pragma unroll
      for (int r = 0; r < 4; ++r) acc_o[ni][r] *= alpha[r];
    // P: C-layout -> A-layout via per-wave LDS strip (wave-private; lgkmcnt handles RAW)
#pragma unroll
    for (int ni = 0; ni < 4; ++ni)
#pragma unroll
      for (int r = 0; r < 4; ++r)
        Ps[wave][quad * 4 + r][ni * 16 + l15] = (bf16)p_v[ni][r];
#pragma unroll
    for (int ks = 0; ks < 2; ++ks) {
      bf16x8 ap = *(const bf16x8*)(&Ps[wave][l15][ks * 32 + quad * 8]);
#pragma unroll
      for (int ni = 0; ni < 4; ++ni) {
        bf16x8 bv = *(const bf16x8*)(&Vt[ni * 16 + l15][ks * 32 + quad * 8]);
        acc_o[ni] = MFMA(ap, bv, acc_o[ni]);
      }
    }
    __syncthreads();
  }
#pragma unroll
  for (int ni = 0; ni < 4; ++ni)
#pragma unroll
    for (int r = 0; r < 4; ++r) {
      int q = qt * 64 + wave * 16 + quad * 4 + r;
      float ov = acc_o[ni][r] / l_r[r];
      O[(size_t)(b * Sq + q) * 1024 + h * 64 + ni * 16 + l15] = (bf16)ov;
    }
}

extern "C" void kernel_launch(void* const* d_in, const int* in_sizes, int n_in,
                              void* d_out, int out_size, void* d_ws, size_t ws_size,
                              hipStream_t stream) {
  (void)in_sizes; (void)n_in; (void)out_size; (void)ws_size;
  const float* x = (const float*)d_in[0];
  const float* ctx = (const float*)d_in[1];
  const float* ln1_g = (const float*)d_in[2];
  const float* ln1_b = (const float*)d_in[3];
  const float* ln2_g = (const float*)d_in[4];
  const float* ln2_b = (const float*)d_in[5];
  const float* ln3_g = (const float*)d_in[6];
  const float* ln3_b = (const float*)d_in[7];
  const float* a1_wq = (const float*)d_in[8];
  const float* a1_wk = (const float*)d_in[9];
  const float* a1_wv = (const float*)d_in[10];
  const float* a1_wo = (const float*)d_in[11];
  const float* a1_bo = (const float*)d_in[12];
  const float* a2_wq = (const float*)d_in[13];
  const float* a2_wk = (const float*)d_in[14];
  const float* a2_wv = (const float*)d_in[15];
  const float* a2_wo = (const float*)d_in[16];
  const float* a2_bo = (const float*)d_in[17];
  const float* ff_w1 = (const float*)d_in[18];
  const float* ff_b1 = (const float*)d_in[19];
  const float* ff_w2 = (const float*)d_in[20];
  const float* ff_b2 = (const float*)d_in[21];
  float* xout = (float*)d_out;

  const int M = 4 * 2048;  // 8192 rows
  char* ws = (char*)d_ws;
  size_t off = 0;
  auto alloc = [&](size_t elems) -> bf16* {
    bf16* p = (bf16*)(ws + off);
    off += ((elems * sizeof(bf16)) + 255) & ~(size_t)255;
    return p;
  };
  bf16* wq1t = alloc((size_t)1024 * 1024);
  bf16* wk1t = alloc((size_t)1024 * 1024);
  bf16* wv1t = alloc((size_t)1024 * 1024);
  bf16* wo1t = alloc((size_t)1024 * 1024);
  bf16* wq2t = alloc((size_t)1024 * 1024);
  bf16* wk2t = alloc((size_t)1024 * 768);
  bf16* wv2t = alloc((size_t)1024 * 768);
  bf16* wo2t = alloc((size_t)1024 * 1024);
  bf16* w1t = alloc((size_t)8192 * 1024);
  bf16* w2t = alloc((size_t)1024 * 4096);
  bf16* lnb = alloc((size_t)M * 1024);
  bf16* qb = alloc((size_t)M * 1024);
  bf16* kb = alloc((size_t)M * 1024);
  bf16* vb = alloc((size_t)M * 1024);
  bf16* ab = alloc((size_t)M * 1024);
  bf16* ctxb = alloc((size_t)308 * 768);
  bf16* kcb = alloc((size_t)308 * 1024);
  bf16* vcb = alloc((size_t)308 * 1024);
  bf16* hgb = alloc((size_t)M * 4096);

  // running residual x lives in d_out (fp32)
  hipMemcpyAsync(xout, x, (size_t)M * 1024 * sizeof(float),
                 hipMemcpyDeviceToDevice, stream);

  // weights -> bf16 transposed (N x K)
  k_transpose_cvt<<<dim3(32, 32), 256, 0, stream>>>(a1_wq, wq1t, 1024, 1024);
  k_transpose_cvt<<<dim3(32, 32), 256, 0, stream>>>(a1_wk, wk1t, 1024, 1024);
  k_transpose_cvt<<<dim3(32, 32), 256, 0, stream>>>(a1_wv, wv1t, 1024, 1024);
  k_transpose_cvt<<<dim3(32, 32), 256, 0, stream>>>(a1_wo, wo1t, 1024, 1024);
  k_transpose_cvt<<<dim3(32, 32), 256, 0, stream>>>(a2_wq, wq2t, 1024, 1024);
  k_transpose_cvt<<<dim3(24, 32), 256, 0, stream>>>(a2_wk, wk2t, 768, 1024);
  k_transpose_cvt<<<dim3(24, 32), 256, 0, stream>>>(a2_wv, wv2t, 768, 1024);
  k_transpose_cvt<<<dim3(32, 32), 256, 0, stream>>>(a2_wo, wo2t, 1024, 1024);
  k_transpose_cvt<<<dim3(32, 256), 256, 0, stream>>>(ff_w1, w1t, 1024, 8192);
  k_transpose_cvt<<<dim3(128, 32), 256, 0, stream>>>(ff_w2, w2t, 4096, 1024);
  k_cvt<<<(308 * 768 + 255) / 256, 256, 0, stream>>>(ctx, ctxb, 308 * 768);

  // ---- self-attention ----
  k_layernorm<<<M, 256, 0, stream>>>(xout, ln1_g, ln1_b, lnb);
  k_gemm_bt<0><<<dim3(64, 8), 256, 0, stream>>>(lnb, wq1t, nullptr, nullptr, qb, M, 1024, 1024);
  k_gemm_bt<0><<<dim3(64, 8), 256, 0, stream>>>(lnb, wk1t, nullptr, nullptr, kb, M, 1024, 1024);
  k_gemm_bt<0><<<dim3(64, 8), 256, 0, stream>>>(lnb, wv1t, nullptr, nullptr, vb, M, 1024, 1024);
  k_flash<<<dim3(32, 16, 4), 256, 0, stream>>>(qb, kb, vb, ab, 2048, 2048, 2048);
  k_gemm_bt<1><<<dim3(64, 8), 256, 0, stream>>>(ab, wo1t, a1_bo, xout, xout, M, 1024, 1024);

  // ---- cross-attention ----
  k_layernorm<<<M, 256, 0, stream>>>(xout, ln2_g, ln2_b, lnb);
  k_gemm_bt<0><<<dim3(64, 8), 256, 0, stream>>>(lnb, wq2t, nullptr, nullptr, qb, M, 1024, 1024);
  k_gemm_bt<0><<<dim3(3, 8), 256, 0, stream>>>(ctxb, wk2t, nullptr, nullptr, kcb, 308, 1024, 768);
  k_gemm_bt<0><<<dim3(3, 8), 256, 0, stream>>>(ctxb, wv2t, nullptr, nullptr, vcb, 308, 1024, 768);
  k_flash<<<dim3(32, 16, 4), 256, 0, stream>>>(qb, kcb, vcb, ab, 2048, 77, 77);
  k_gemm_bt<1><<<dim3(64, 8), 256, 0, stream>>>(ab, wo2t, a2_bo, xout, xout, M, 1024, 1024);

  // ---- GeGLU feed-forward ----
  k_layernorm<<<M, 256, 0, stream>>>(xout, ln3_g, ln3_b, lnb);
  k_gemm_geglu<<<dim3(64, 32), 256, 0, stream>>>(lnb, w1t, ff_b1, hgb, M, 1024);
  k_gemm_bt<1><<<dim3(64, 8), 256, 0, stream>>>(hgb, w2t, ff_b2, xout, xout, M, 1024, 4096);
}

// Round 2
// 1192.951 us; speedup vs baseline: 1.9399x; 1.9399x over previous
//
#include <hip/hip_runtime.h>
#include <hip/hip_bf16.h>
#include <math.h>

typedef __bf16 bf16;
typedef __bf16 bf16x8 __attribute__((ext_vector_type(8)));
typedef float f32x4 __attribute__((ext_vector_type(4)));

#define MFMA(a, b, c) __builtin_amdgcn_mfma_f32_16x16x32_bf16((a), (b), (c), 0, 0, 0)

static __device__ __forceinline__ bf16x8 bzero8() {
  bf16x8 v;
#pragma unroll
  for (int i = 0; i < 8; ++i) v[i] = (bf16)0.0f;
  return v;
}

// ---------- W (K x N fp32, row-major) -> Wt (N x K bf16, row-major) ----------
__global__ void k_transpose_cvt(const float* __restrict__ W, bf16* __restrict__ Wt,
                                int K, int N) {
  __shared__ float tile[32][33];
  int k0 = blockIdx.x * 32, n0 = blockIdx.y * 32;
  int tx = threadIdx.x & 31, ty = threadIdx.x >> 5;
  for (int i = ty; i < 32; i += 8)
    tile[i][tx] = W[(size_t)(k0 + i) * N + (n0 + tx)];
  __syncthreads();
  for (int i = ty; i < 32; i += 8)
    Wt[(size_t)(n0 + i) * K + (k0 + tx)] = (bf16)tile[tx][i];
}

// ---------- fp32 -> bf16 flat convert ----------
__global__ void k_cvt(const float* __restrict__ in, bf16* __restrict__ out, int n) {
  int i = blockIdx.x * 256 + threadIdx.x;
  if (i < n) out[i] = (bf16)in[i];
}

// ---------- LayerNorm over D=1024, one block per row, bf16 out ----------
__global__ void k_layernorm(const float* __restrict__ x, const float* __restrict__ g,
                            const float* __restrict__ b, bf16* __restrict__ out) {
  int row = blockIdx.x;
  float4 v = ((const float4*)(x + (size_t)row * 1024))[threadIdx.x];
  float s = v.x + v.y + v.z + v.w;
  float ss = v.x * v.x + v.y * v.y + v.z * v.z + v.w * v.w;
#pragma unroll
  for (int off = 1; off < 64; off <<= 1) {
    s += __shfl_xor(s, off);
    ss += __shfl_xor(ss, off);
  }
  __shared__ float sm[4], sm2[4];
  int w = threadIdx.x >> 6;
  if ((threadIdx.x & 63) == 0) { sm[w] = s; sm2[w] = ss; }
  __syncthreads();
  s = sm[0] + sm[1] + sm[2] + sm[3];
  ss = sm2[0] + sm2[1] + sm2[2] + sm2[3];
  float mu = s * (1.0f / 1024.0f);
  float var = ss * (1.0f / 1024.0f) - mu * mu;
  float rs = rsqrtf(var + 1e-5f);
  float4 gg = ((const float4*)g)[threadIdx.x];
  float4 bb = ((const float4*)b)[threadIdx.x];
  bf16* o = out + (size_t)row * 1024 + threadIdx.x * 4;
  o[0] = (bf16)((v.x - mu) * rs * gg.x + bb.x);
  o[1] = (bf16)((v.y - mu) * rs * gg.y + bb.y);
  o[2] = (bf16)((v.z - mu) * rs * gg.z + bb.z);
  o[3] = (bf16)((v.w - mu) * rs * gg.w + bb.w);
}

// ---------- GEMM: C[M,N] = A[M,K] @ Bt[N,K]^T  (bf16 in, fp32 acc) ----------
// EPI 0: store bf16 C.  EPI 1: store fp32 C = acc + bias[col] + res[row,col].
template <int EPI>
__global__ void k_gemm_bt(const bf16* __restrict__ A, const bf16* __restrict__ Bt,
                          const float* __restrict__ bias, const float* __restrict__ res,
                          void* __restrict__ Cp, int M, int N, int K) {
  __shared__ __attribute__((aligned(16))) bf16 As[128][40];
  __shared__ __attribute__((aligned(16))) bf16 Bs[128][40];
  int m0 = blockIdx.x * 128, n0 = blockIdx.y * 128;
  int tid = threadIdx.x, lane = tid & 63, wave = tid >> 6;
  int wm = (wave >> 1) * 64, wn = (wave & 1) * 64;
  int quad = lane >> 4, l15 = lane & 15;
  f32x4 acc[4][4];
#pragma unroll
  for (int i = 0; i < 4; ++i)
#pragma unroll
    for (int j = 0; j < 4; ++j)
#pragma unroll
      for (int r = 0; r < 4; ++r) acc[i][j][r] = 0.0f;
  int srow = tid >> 2, scol = (tid & 3) * 8;
  for (int k0 = 0; k0 < K; k0 += 32) {
#pragma unroll
    for (int rr = 0; rr < 2; ++rr) {
      int r = srow + rr * 64;
      int gm = m0 + r;
      bf16x8 av = bzero8();
      if (gm < M) av = *(const bf16x8*)(A + (size_t)gm * K + k0 + scol);
      *(bf16x8*)(&As[r][scol]) = av;
      int gn = n0 + r;
      bf16x8 bv = bzero8();
      if (gn < N) bv = *(const bf16x8*)(Bt + (size_t)gn * K + k0 + scol);
      *(bf16x8*)(&Bs[r][scol]) = bv;
    }
    __syncthreads();
    bf16x8 af[4], bfr[4];
#pragma unroll
    for (int i = 0; i < 4; ++i) af[i] = *(const bf16x8*)(&As[wm + i * 16 + l15][quad * 8]);
#pragma unroll
    for (int i = 0; i < 4; ++i) bfr[i] = *(const bf16x8*)(&Bs[wn + i * 16 + l15][quad * 8]);
#pragma unroll
    for (int mi = 0; mi < 4; ++mi)
#pragma unroll
      for (int ni = 0; ni < 4; ++ni)
        acc[mi][ni] = MFMA(af[mi], bfr[ni], acc[mi][ni]);
    __syncthreads();
  }
#pragma unroll
  for (int mi = 0; mi < 4; ++mi) {
#pragma unroll
    for (int r = 0; r < 4; ++r) {
      int row = m0 + wm + mi * 16 + quad * 4 + r;
      if (row >= M) continue;
#pragma unroll
      for (int ni = 0; ni < 4; ++ni) {
        int col = n0 + wn + ni * 16 + l15;
        float v = acc[mi][ni][r];
        if (EPI == 0) {
          ((bf16*)Cp)[(size_t)row * N + col] = (bf16)v;
        } else {
          ((float*)Cp)[(size_t)row * N + col] =
              v + bias[col] + res[(size_t)row * N + col];
        }
      }
    }
  }
}

// ---------- GEMM + GeGLU: Hg[M,4096] = (A@W1t[:4096]+b1u) * gelu(A@W1t[4096:]+b1g)
// 128x64 output tile per block, dual accumulators sized to match k_gemm_bt's
// register footprint (16 f32x4/wave total) -- avoids the spill seen at 128x128.
__global__ void k_gemm_geglu(const bf16* __restrict__ A, const bf16* __restrict__ W1t,
                             const float* __restrict__ b1, bf16* __restrict__ Hg,
                             int M, int K) {
  __shared__ __attribute__((aligned(16))) bf16 As[128][40];
  __shared__ __attribute__((aligned(16))) bf16 Bu[64][40];
  __shared__ __attribute__((aligned(16))) bf16 Bg[64][40];
  const int N = 4096;
  int m0 = blockIdx.x * 128, n0 = blockIdx.y * 64;
  int tid = threadIdx.x, lane = tid & 63, wave = tid >> 6;
  int wm = (wave >> 1) * 64, wn = (wave & 1) * 32;
  int quad = lane >> 4, l15 = lane & 15;
  f32x4 accu[4][2], accg[4][2];
#pragma unroll
  for (int i = 0; i < 4; ++i)
#pragma unroll
    for (int j = 0; j < 2; ++j)
#pragma unroll
      for (int r = 0; r < 4; ++r) { accu[i][j][r] = 0.0f; accg[i][j][r] = 0.0f; }
  int srow = tid >> 2, scol = (tid & 3) * 8;
  for (int k0 = 0; k0 < K; k0 += 32) {
#pragma unroll
    for (int rr = 0; rr < 2; ++rr) {
      int r = srow + rr * 64;
      *(bf16x8*)(&As[r][scol]) = *(const bf16x8*)(A + (size_t)(m0 + r) * K + k0 + scol);
    }
    *(bf16x8*)(&Bu[srow][scol]) = *(const bf16x8*)(W1t + (size_t)(n0 + srow) * K + k0 + scol);
    *(bf16x8*)(&Bg[srow][scol]) = *(const bf16x8*)(W1t + (size_t)(n0 + srow + 4096) * K + k0 + scol);
    __syncthreads();
    bf16x8 af[4], bu[2], bg[2];
#pragma unroll
    for (int i = 0; i < 4; ++i) af[i] = *(const bf16x8*)(&As[wm + i * 16 + l15][quad * 8]);
#pragma unroll
    for (int i = 0; i < 2; ++i) bu[i] = *(const bf16x8*)(&Bu[wn + i * 16 + l15][quad * 8]);
#pragma unroll
    for (int i = 0; i < 2; ++i) bg[i] = *(const bf16x8*)(&Bg[wn + i * 16 + l15][quad * 8]);
#pragma unroll
    for (int mi = 0; mi < 4; ++mi)
#pragma unroll
      for (int ni = 0; ni < 2; ++ni) {
        accu[mi][ni] = MFMA(af[mi], bu[ni], accu[mi][ni]);
        accg[mi][ni] = MFMA(af[mi], bg[ni], accg[mi][ni]);
      }
    __syncthreads();
  }
#pragma unroll
  for (int mi = 0; mi < 4; ++mi)
#pragma unroll
    for (int r = 0; r < 4; ++r) {
      int row = m0 + wm + mi * 16 + quad * 4 + r;
#pragma unroll
      for (int ni = 0; ni < 2; ++ni) {
        int col = n0 + wn + ni * 16 + l15;
        float u = accu[mi][ni][r] + b1[col];
        float g = accg[mi][ni][r] + b1[col + 4096];
        float ge = 0.5f * g * (1.0f + erff(g * 0.70710678118654752f));
        Hg[(size_t)row * N + col] = (bf16)(u * ge);
      }
    }
}

// ---------- Flash attention: 64 q-rows per block, 64-key chunks ----------
// Q: (B*Sq,1024) bf16, head h at col h*64. K/V: (B*kvrows,1024) bf16. O: bf16.
__global__ void k_flash(const bf16* __restrict__ Q, const bf16* __restrict__ Kb,
                        const bf16* __restrict__ Vb, bf16* __restrict__ O,
                        int Sq, int Sk, int kvrows) {
  __shared__ __attribute__((aligned(16))) bf16 Qs[64][72];
  __shared__ __attribute__((aligned(16))) bf16 Ks[64][72];
  __shared__ __attribute__((aligned(16))) bf16 Vt[64][72];
  __shared__ __attribute__((aligned(16))) bf16 Ps[4][16][72];
  int qt = blockIdx.x, h = blockIdx.y, b = blockIdx.z;
  int tid = threadIdx.x, lane = tid & 63, wave = tid >> 6;
  int quad = lane >> 4, l15 = lane & 15;
  {
    int r = tid >> 2, c0 = (tid & 3) * 16;
    const bf16* src = Q + (size_t)(b * Sq + qt * 64 + r) * 1024 + h * 64 + c0;
    *(bf16x8*)(&Qs[r][c0]) = *(const bf16x8*)(src);
    *(bf16x8*)(&Qs[r][c0 + 8]) = *(const bf16x8*)(src + 8);
  }
  float m_r[4], l_r[4];
  f32x4 acc_o[4];
#pragma unroll
  for (int r = 0; r < 4; ++r) { m_r[r] = -1e30f; l_r[r] = 0.0f; }
#pragma unroll
  for (int ni = 0; ni < 4; ++ni)
#pragma unroll
    for (int r = 0; r < 4; ++r) acc_o[ni][r] = 0.0f;

  for (int k0 = 0; k0 < Sk; k0 += 64) {
    {
      int r = tid >> 2, c0 = (tid & 3) * 16;
      int krow = k0 + r;
      bf16x8 k1 = bzero8(), k2 = bzero8(), v1 = bzero8(), v2 = bzero8();
      if (krow < Sk) {
        const bf16* ks = Kb + (size_t)(b * kvrows + krow) * 1024 + h * 64 + c0;
        k1 = *(const bf16x8*)ks;
        k2 = *(const bf16x8*)(ks + 8);
        const bf16* vs = Vb + (size_t)(b * kvrows + krow) * 1024 + h * 64 + c0;
        v1 = *(const bf16x8*)vs;
        v2 = *(const bf16x8*)(vs + 8);
      }
      *(bf16x8*)(&Ks[r][c0]) = k1;
      *(bf16x8*)(&Ks[r][c0 + 8]) = k2;
#pragma unroll
      for (int j = 0; j < 8; ++j) { Vt[c0 + j][r] = v1[j]; Vt[c0 + 8 + j][r] = v2[j]; }
    }
    __syncthreads();

    // S = Q(16 rows of this wave) @ K^T  -> sacc[ni][r] = S[quad*4+r][ni*16+l15]
    f32x4 sacc[4];
#pragma unroll
    for (int ni = 0; ni < 4; ++ni)
#pragma unroll
      for (int r = 0; r < 4; ++r) sacc[ni][r] = 0.0f;
#pragma unroll
    for (int ks = 0; ks < 2; ++ks) {
      bf16x8 aq = *(const bf16x8*)(&Qs[wave * 16 + l15][ks * 32 + quad * 8]);
#pragma unroll
      for (int ni = 0; ni < 4; ++ni) {
        bf16x8 bk = *(const bf16x8*)(&Ks[ni * 16 + l15][ks * 32 + quad * 8]);
        sacc[ni] = MFMA(aq, bk, sacc[ni]);
      }
    }
    float s_v[4][4];
#pragma unroll
    for (int ni = 0; ni < 4; ++ni)
#pragma unroll
      for (int r = 0; r < 4; ++r) {
        float sv = sacc[ni][r] * 0.125f;  // DH^-0.5
        if (k0 + ni * 16 + l15 >= Sk) sv = -1e30f;
        s_v[ni][r] = sv;
      }
    float alpha[4];
#pragma unroll
    for (int r = 0; r < 4; ++r) {
      float v = fmaxf(fmaxf(s_v[0][r], s_v[1][r]), fmaxf(s_v[2][r], s_v[3][r]));
#pragma unroll
      for (int off = 1; off < 16; off <<= 1) v = fmaxf(v, __shfl_xor(v, off));
      float mn = fmaxf(m_r[r], v);
      alpha[r] = __expf(m_r[r] - mn);
      m_r[r] = mn;
    }
    float p_v[4][4];
#pragma unroll
    for (int ni = 0; ni < 4; ++ni)
#pragma unroll
      for (int r = 0; r < 4; ++r) p_v[ni][r] = __expf(s_v[ni][r] - m_r[r]);
#pragma unroll
    for (int r = 0; r < 4; ++r) {
      float v = p_v[0][r] + p_v[1][r] + p_v[2][r] + p_v[3][r];
#pragma unroll
      for (int off = 1; off < 16; off <<= 1) v += __shfl_xor(v, off);
      l_r[r] = l_r[r] * alpha[r] + v;
    }
#pragma unroll
    for (int ni = 0; ni < 4; ++ni)
#pragma unroll
      for (int r = 0; r < 4; ++r) acc_o[ni][r] *= alpha[r];
    // P: C-layout -> A-layout via per-wave LDS strip (wave-private; lgkmcnt handles RAW)
#pragma unroll
    for (int ni = 0; ni < 4; ++ni)
#pragma unroll
      for (int r = 0; r < 4; ++r)
        Ps[wave][quad * 4 + r][ni * 16 + l15] = (bf16)p_v[ni][r];
#pragma unroll
    for (int ks = 0; ks < 2; ++ks) {
      bf16x8 ap = *(const bf16x8*)(&Ps[wave][l15][ks * 32 + quad * 8]);
#pragma unroll
      for (int ni = 0; ni < 4; ++ni) {
        bf16x8 bv = *(const bf16x8*)(&Vt[ni * 16 + l15][ks * 32 + quad * 8]);
        acc_o[ni] = MFMA(ap, bv, acc_o[ni]);
      }
    }
    __syncthreads();
  }
#pragma unroll
  for (int ni = 0; ni < 4; ++ni)
#pragma unroll
    for (int r = 0; r < 4; ++r) {
      int q = qt * 64 + wave * 16 + quad * 4 + r;
      float ov = acc_o[ni][r] / l_r[r];
      O[(size_t)(b * Sq + q) * 1024 + h * 64 + ni * 16 + l15] = (bf16)ov;
    }
}

extern "C" void kernel_launch(void* const* d_in, const int* in_sizes, int n_in,
                              void* d_out, int out_size, void* d_ws, size_t ws_size,
                              hipStream_t stream) {
  (void)in_sizes; (void)n_in; (void)out_size; (void)ws_size;
  const float* x = (const float*)d_in[0];
  const float* ctx = (const float*)d_in[1];
  const float* ln1_g = (const float*)d_in[2];
  const float* ln1_b = (const float*)d_in[3];
  const float* ln2_g = (const float*)d_in[4];
  const float* ln2_b = (const float*)d_in[5];
  const float* ln3_g = (const float*)d_in[6];
  const float* ln3_b = (const float*)d_in[7];
  const float* a1_wq = (const float*)d_in[8];
  const float* a1_wk = (const float*)d_in[9];
  const float* a1_wv = (const float*)d_in[10];
  const float* a1_wo = (const float*)d_in[11];
  const float* a1_bo = (const float*)d_in[12];
  const float* a2_wq = (const float*)d_in[13];
  const float* a2_wk = (const float*)d_in[14];
  const float* a2_wv = (const float*)d_in[15];
  const float* a2_wo = (const float*)d_in[16];
  const float* a2_bo = (const float*)d_in[17];
  const float* ff_w1 = (const float*)d_in[18];
  const float* ff_b1 = (const float*)d_in[19];
  const float* ff_w2 = (const float*)d_in[20];
  const float* ff_b2 = (const float*)d_in[21];
  float* xout = (float*)d_out;

  const int M = 4 * 2048;  // 8192 rows
  char* ws = (char*)d_ws;
  size_t off = 0;
  auto alloc = [&](size_t elems) -> bf16* {
    bf16* p = (bf16*)(ws + off);
    off += ((elems * sizeof(bf16)) + 255) & ~(size_t)255;
    return p;
  };
  bf16* wq1t = alloc((size_t)1024 * 1024);
  bf16* wk1t = alloc((size_t)1024 * 1024);
  bf16* wv1t = alloc((size_t)1024 * 1024);
  bf16* wo1t = alloc((size_t)1024 * 1024);
  bf16* wq2t = alloc((size_t)1024 * 1024);
  bf16* wk2t = alloc((size_t)1024 * 768);
  bf16* wv2t = alloc((size_t)1024 * 768);
  bf16* wo2t = alloc((size_t)1024 * 1024);
  bf16* w1t = alloc((size_t)8192 * 1024);
  bf16* w2t = alloc((size_t)1024 * 4096);
  bf16* lnb = alloc((size_t)M * 1024);
  bf16* qb = alloc((size_t)M * 1024);
  bf16* kb = alloc((size_t)M * 1024);
  bf16* vb = alloc((size_t)M * 1024);
  bf16* ab = alloc((size_t)M * 1024);
  bf16* ctxb = alloc((size_t)308 * 768);
  bf16* kcb = alloc((size_t)308 * 1024);
  bf16* vcb = alloc((size_t)308 * 1024);
  bf16* hgb = alloc((size_t)M * 4096);

  // running residual x lives in d_out (fp32)
  hipMemcpyAsync(xout, x, (size_t)M * 1024 * sizeof(float),
                 hipMemcpyDeviceToDevice, stream);

  // weights -> bf16 transposed (N x K)
  k_transpose_cvt<<<dim3(32, 32), 256, 0, stream>>>(a1_wq, wq1t, 1024, 1024);
  k_transpose_cvt<<<dim3(32, 32), 256, 0, stream>>>(a1_wk, wk1t, 1024, 1024);
  k_transpose_cvt<<<dim3(32, 32), 256, 0, stream>>>(a1_wv, wv1t, 1024, 1024);
  k_transpose_cvt<<<dim3(32, 32), 256, 0, stream>>>(a1_wo, wo1t, 1024, 1024);
  k_transpose_cvt<<<dim3(32, 32), 256, 0, stream>>>(a2_wq, wq2t, 1024, 1024);
  k_transpose_cvt<<<dim3(24, 32), 256, 0, stream>>>(a2_wk, wk2t, 768, 1024);
  k_transpose_cvt<<<dim3(24, 32), 256, 0, stream>>>(a2_wv, wv2t, 768, 1024);
  k_transpose_cvt<<<dim3(32, 32), 256, 0, stream>>>(a2_wo, wo2t, 1024, 1024);
  k_transpose_cvt<<<dim3(32, 256), 256, 0, stream>>>(ff_w1, w1t, 1024, 8192);
  k_transpose_cvt<<<dim3(128, 32), 256, 0, stream>>>(ff_w2, w2t, 4096, 1024);
  k_cvt<<<(308 * 768 + 255) / 256, 256, 0, stream>>>(ctx, ctxb, 308 * 768);

  // ---- self-attention ----
  k_layernorm<<<M, 256, 0, stream>>>(xout, ln1_g, ln1_b, lnb);
  k_gemm_bt<0><<<dim3(64, 8), 256, 0, stream>>>(lnb, wq1t, nullptr, nullptr, qb, M, 1024, 1024);
  k_gemm_bt<0><<<dim3(64, 8), 256, 0, stream>>>(lnb, wk1t, nullptr, nullptr, kb, M, 1024, 1024);
  k_gemm_bt<0><<<dim3(64, 8), 256, 0, stream>>>(lnb, wv1t, nullptr, nullptr, vb, M, 1024, 1024);
  k_flash<<<dim3(32, 16, 4), 256, 0, stream>>>(qb, kb, vb, ab, 2048, 2048, 2048);
  k_gemm_bt<1><<<dim3(64, 8), 256, 0, stream>>>(ab, wo1t, a1_bo, xout, xout, M, 1024, 1024);

  // ---- cross-attention ----
  k_layernorm<<<M, 256, 0, stream>>>(xout, ln2_g, ln2_b, lnb);
  k_gemm_bt<0><<<dim3(64, 8), 256, 0, stream>>>(lnb, wq2t, nullptr, nullptr, qb, M, 1024, 1024);
  k_gemm_bt<0><<<dim3(3, 8), 256, 0, stream>>>(ctxb, wk2t, nullptr, nullptr, kcb, 308, 1024, 768);
  k_gemm_bt<0><<<dim3(3, 8), 256, 0, stream>>>(ctxb, wv2t, nullptr, nullptr, vcb, 308, 1024, 768);
  k_flash<<<dim3(32, 16, 4), 256, 0, stream>>>(qb, kcb, vcb, ab, 2048, 77, 77);
  k_gemm_bt<1><<<dim3(64, 8), 256, 0, stream>>>(ab, wo2t, a2_bo, xout, xout, M, 1024, 1024);

  // ---- GeGLU feed-forward ----
  k_layernorm<<<M, 256, 0, stream>>>(xout, ln3_g, ln3_b, lnb);
  k_gemm_geglu<<<dim3(64, 64), 256, 0, stream>>>(lnb, w1t, ff_b1, hgb, M, 1024);
  k_gemm_bt<1><<<dim3(64, 8), 256, 0, stream>>>(hgb, w2t, ff_b2, xout, xout, M, 1024, 4096);
}

// Round 3
// 990.083 us; speedup vs baseline: 2.3373x; 1.2049x over previous
//
#include <hip/hip_runtime.h>
#include <hip/hip_bf16.h>
#include <math.h>

typedef __bf16 bf16;
typedef __bf16 bf16x8 __attribute__((ext_vector_type(8)));
typedef float f32x4 __attribute__((ext_vector_type(4)));

#define MFMA(a, b, c) __builtin_amdgcn_mfma_f32_16x16x32_bf16((a), (b), (c), 0, 0, 0)

// async global->LDS, 16B per lane. LDS dest must be wave-uniform base + lane*16.
static __device__ __forceinline__ void gl16(const bf16* g, bf16* l) {
  __builtin_amdgcn_global_load_lds(
      (const __attribute__((address_space(1))) void*)g,
      (__attribute__((address_space(3))) void*)l, 16, 0, 0);
}

static __device__ __forceinline__ bf16x8 bzero8() {
  bf16x8 v;
#pragma unroll
  for (int i = 0; i < 8; ++i) v[i] = (bf16)0.0f;
  return v;
}

// ---------- W (K x N fp32, row-major) -> Wt (N x K bf16, row-major) ----------
__global__ void k_transpose_cvt(const float* __restrict__ W, bf16* __restrict__ Wt,
                                int K, int N) {
  __shared__ float tile[32][33];
  int k0 = blockIdx.x * 32, n0 = blockIdx.y * 32;
  int tx = threadIdx.x & 31, ty = threadIdx.x >> 5;
  for (int i = ty; i < 32; i += 8)
    tile[i][tx] = W[(size_t)(k0 + i) * N + (n0 + tx)];
  __syncthreads();
  for (int i = ty; i < 32; i += 8)
    Wt[(size_t)(n0 + i) * K + (k0 + tx)] = (bf16)tile[tx][i];
}

// ---------- fp32 -> bf16 flat convert ----------
__global__ void k_cvt(const float* __restrict__ in, bf16* __restrict__ out, int n) {
  int i = blockIdx.x * 256 + threadIdx.x;
  if (i < n) out[i] = (bf16)in[i];
}

// ---------- LayerNorm over D=1024, one block per row, bf16 out ----------
__global__ void k_layernorm(const float* __restrict__ x, const float* __restrict__ g,
                            const float* __restrict__ b, bf16* __restrict__ out) {
  int row = blockIdx.x;
  float4 v = ((const float4*)(x + (size_t)row * 1024))[threadIdx.x];
  float s = v.x + v.y + v.z + v.w;
  float ss = v.x * v.x + v.y * v.y + v.z * v.z + v.w * v.w;
#pragma unroll
  for (int off = 1; off < 64; off <<= 1) {
    s += __shfl_xor(s, off);
    ss += __shfl_xor(ss, off);
  }
  __shared__ float sm[4], sm2[4];
  int w = threadIdx.x >> 6;
  if ((threadIdx.x & 63) == 0) { sm[w] = s; sm2[w] = ss; }
  __syncthreads();
  s = sm[0] + sm[1] + sm[2] + sm[3];
  ss = sm2[0] + sm2[1] + sm2[2] + sm2[3];
  float mu = s * (1.0f / 1024.0f);
  float var = ss * (1.0f / 1024.0f) - mu * mu;
  float rs = rsqrtf(var + 1e-5f);
  float4 gg = ((const float4*)g)[threadIdx.x];
  float4 bb = ((const float4*)b)[threadIdx.x];
  bf16* o = out + (size_t)row * 1024 + threadIdx.x * 4;
  o[0] = (bf16)((v.x - mu) * rs * gg.x + bb.x);
  o[1] = (bf16)((v.y - mu) * rs * gg.y + bb.y);
  o[2] = (bf16)((v.z - mu) * rs * gg.z + bb.z);
  o[3] = (bf16)((v.w - mu) * rs * gg.w + bb.w);
}

// ---------- GEMM: C[M,N] = A[M,K] @ Bt[N,K]^T  (bf16 in, fp32 acc) ----------
// m97-style: unpadded [128][32] LDS, global_load_lds width-16 staging.
// Loads are unguarded (OOB rows stay inside d_ws); stores are row-guarded.
// EPI 0: store bf16 C.  EPI 1: store fp32 C = acc + bias[col] + res[row,col].
template <int EPI>
__global__ __launch_bounds__(256, 2)
void k_gemm_bt(const bf16* __restrict__ A, const bf16* __restrict__ Bt,
               const float* __restrict__ bias, const float* __restrict__ res,
               void* __restrict__ Cp, int M, int N, int K) {
  __shared__ __attribute__((aligned(16))) bf16 As[128 * 32];
  __shared__ __attribute__((aligned(16))) bf16 Bs[128 * 32];
  int m0 = blockIdx.x * 128, n0 = blockIdx.y * 128;
  int tid = threadIdx.x, lane = tid & 63, wave = tid >> 6;
  int wm = (wave >> 1) * 64, wn = (wave & 1) * 64;
  int quad = lane >> 4, l15 = lane & 15;
  f32x4 acc[4][4];
#pragma unroll
  for (int i = 0; i < 4; ++i)
#pragma unroll
    for (int j = 0; j < 4; ++j)
#pragma unroll
      for (int r = 0; r < 4; ++r) acc[i][j][r] = 0.0f;
  // staging map: wave covers 16 consecutive rows; lane i -> row 16w + i/4, col (i%4)*8
  int srow = wave * 16 + (lane >> 2), scol = (lane & 3) * 8;
  const bf16* ga = A + (size_t)(m0 + srow) * K + scol;
  const bf16* gb = Bt + (size_t)(n0 + srow) * K + scol;
  bf16* la = As + srow * 32 + scol;
  bf16* lb = Bs + srow * 32 + scol;
  for (int k0 = 0; k0 < K; k0 += 32) {
    gl16(ga, la);
    gl16(ga + (size_t)64 * K, la + 64 * 32);
    gl16(gb, lb);
    gl16(gb + (size_t)64 * K, lb + 64 * 32);
    ga += 32; gb += 32;
    __syncthreads();
    bf16x8 af[4], bfr[4];
#pragma unroll
    for (int i = 0; i < 4; ++i) af[i] = *(const bf16x8*)(&As[(wm + i * 16 + l15) * 32 + quad * 8]);
#pragma unroll
    for (int i = 0; i < 4; ++i) bfr[i] = *(const bf16x8*)(&Bs[(wn + i * 16 + l15) * 32 + quad * 8]);
#pragma unroll
    for (int mi = 0; mi < 4; ++mi)
#pragma unroll
      for (int ni = 0; ni < 4; ++ni)
        acc[mi][ni] = MFMA(af[mi], bfr[ni], acc[mi][ni]);
    __syncthreads();
  }
#pragma unroll
  for (int mi = 0; mi < 4; ++mi) {
#pragma unroll
    for (int r = 0; r < 4; ++r) {
      int row = m0 + wm + mi * 16 + quad * 4 + r;
      if (row >= M) continue;
#pragma unroll
      for (int ni = 0; ni < 4; ++ni) {
        int col = n0 + wn + ni * 16 + l15;
        float v = acc[mi][ni][r];
        if (EPI == 0) {
          ((bf16*)Cp)[(size_t)row * N + col] = (bf16)v;
        } else {
          ((float*)Cp)[(size_t)row * N + col] =
              v + bias[col] + res[(size_t)row * N + col];
        }
      }
    }
  }
}

// ---------- GEMM + GeGLU: Hg[M,4096] = (A@W1t[:4096]+b1u) * gelu(A@W1t[4096:]+b1g)
// 128x64 tile (dual acc fits registers); m97-style async staging.
__global__ __launch_bounds__(256, 2)
void k_gemm_geglu(const bf16* __restrict__ A, const bf16* __restrict__ W1t,
                  const float* __restrict__ b1, bf16* __restrict__ Hg,
                  int M, int K) {
  __shared__ __attribute__((aligned(16))) bf16 As[128 * 32];
  __shared__ __attribute__((aligned(16))) bf16 Bu[64 * 32];
  __shared__ __attribute__((aligned(16))) bf16 Bg[64 * 32];
  const int N = 4096;
  int m0 = blockIdx.x * 128, n0 = blockIdx.y * 64;
  int tid = threadIdx.x, lane = tid & 63, wave = tid >> 6;
  int wm = (wave >> 1) * 64, wn = (wave & 1) * 32;
  int quad = lane >> 4, l15 = lane & 15;
  f32x4 accu[4][2], accg[4][2];
#pragma unroll
  for (int i = 0; i < 4; ++i)
#pragma unroll
    for (int j = 0; j < 2; ++j)
#pragma unroll
      for (int r = 0; r < 4; ++r) { accu[i][j][r] = 0.0f; accg[i][j][r] = 0.0f; }
  int srow = wave * 16 + (lane >> 2), scol = (lane & 3) * 8;
  const bf16* ga = A + (size_t)(m0 + srow) * K + scol;
  const bf16* gu = W1t + (size_t)(n0 + srow) * K + scol;
  const bf16* gg = W1t + (size_t)(n0 + srow + 4096) * K + scol;
  bf16* la = As + srow * 32 + scol;
  bf16* lu = Bu + srow * 32 + scol;
  bf16* lg = Bg + srow * 32 + scol;
  for (int k0 = 0; k0 < K; k0 += 32) {
    gl16(ga, la);
    gl16(ga + (size_t)64 * K, la + 64 * 32);
    gl16(gu, lu);
    gl16(gg, lg);
    ga += 32; gu += 32; gg += 32;
    __syncthreads();
    bf16x8 af[4], bu[2], bg[2];
#pragma unroll
    for (int i = 0; i < 4; ++i) af[i] = *(const bf16x8*)(&As[(wm + i * 16 + l15) * 32 + quad * 8]);
#pragma unroll
    for (int i = 0; i < 2; ++i) bu[i] = *(const bf16x8*)(&Bu[(wn + i * 16 + l15) * 32 + quad * 8]);
#pragma unroll
    for (int i = 0; i < 2; ++i) bg[i] = *(const bf16x8*)(&Bg[(wn + i * 16 + l15) * 32 + quad * 8]);
#pragma unroll
    for (int mi = 0; mi < 4; ++mi)
#pragma unroll
      for (int ni = 0; ni < 2; ++ni) {
        accu[mi][ni] = MFMA(af[mi], bu[ni], accu[mi][ni]);
        accg[mi][ni] = MFMA(af[mi], bg[ni], accg[mi][ni]);
      }
    __syncthreads();
  }
#pragma unroll
  for (int mi = 0; mi < 4; ++mi)
#pragma unroll
    for (int r = 0; r < 4; ++r) {
      int row = m0 + wm + mi * 16 + quad * 4 + r;
#pragma unroll
      for (int ni = 0; ni < 2; ++ni) {
        int col = n0 + wn + ni * 16 + l15;
        float u = accu[mi][ni][r] + b1[col];
        float g = accg[mi][ni][r] + b1[col + 4096];
        float ge = 0.5f * g * (1.0f + erff(g * 0.70710678118654752f));
        Hg[(size_t)row * N + col] = (bf16)(u * ge);
      }
    }
}

// ---------- Flash attention: 64 q-rows per block, 64-key chunks ----------
// Q: (B*Sq,1024) bf16, head h at col h*64. K/V: (B*kvrows,1024) bf16. O: bf16.
__global__ __launch_bounds__(256, 2)
void k_flash(const bf16* __restrict__ Q, const bf16* __restrict__ Kb,
             const bf16* __restrict__ Vb, bf16* __restrict__ O,
             int Sq, int Sk, int kvrows) {
  __shared__ __attribute__((aligned(16))) bf16 Qs[64][72];
  __shared__ __attribute__((aligned(16))) bf16 Ks[64][72];
  __shared__ __attribute__((aligned(16))) bf16 Vt[64][72];
  __shared__ __attribute__((aligned(16))) bf16 Ps[4][16][72];
  int qt = blockIdx.x, h = blockIdx.y, b = blockIdx.z;
  int tid = threadIdx.x, lane = tid & 63, wave = tid >> 6;
  int quad = lane >> 4, l15 = lane & 15;
  {
    int r = tid >> 2, c0 = (tid & 3) * 16;
    const bf16* src = Q + (size_t)(b * Sq + qt * 64 + r) * 1024 + h * 64 + c0;
    *(bf16x8*)(&Qs[r][c0]) = *(const bf16x8*)(src);
    *(bf16x8*)(&Qs[r][c0 + 8]) = *(const bf16x8*)(src + 8);
  }
  float m_r[4], l_r[4];
  f32x4 acc_o[4];
#pragma unroll
  for (int r = 0; r < 4; ++r) { m_r[r] = -1e30f; l_r[r] = 0.0f; }
#pragma unroll
  for (int ni = 0; ni < 4; ++ni)
#pragma unroll
    for (int r = 0; r < 4; ++r) acc_o[ni][r] = 0.0f;

  for (int k0 = 0; k0 < Sk; k0 += 64) {
    {
      int r = tid >> 2, c0 = (tid & 3) * 16;
      int krow = k0 + r;
      bf16x8 k1 = bzero8(), k2 = bzero8(), v1 = bzero8(), v2 = bzero8();
      if (krow < Sk) {
        const bf16* ks = Kb + (size_t)(b * kvrows + krow) * 1024 + h * 64 + c0;
        k1 = *(const bf16x8*)ks;
        k2 = *(const bf16x8*)(ks + 8);
        const bf16* vs = Vb + (size_t)(b * kvrows + krow) * 1024 + h * 64 + c0;
        v1 = *(const bf16x8*)vs;
        v2 = *(const bf16x8*)(vs + 8);
      }
      *(bf16x8*)(&Ks[r][c0]) = k1;
      *(bf16x8*)(&Ks[r][c0 + 8]) = k2;
#pragma unroll
      for (int j = 0; j < 8; ++j) { Vt[c0 + j][r] = v1[j]; Vt[c0 + 8 + j][r] = v2[j]; }
    }
    __syncthreads();

    // S = Q(16 rows of this wave) @ K^T  -> sacc[ni][r] = S[quad*4+r][ni*16+l15]
    f32x4 sacc[4];
#pragma unroll
    for (int ni = 0; ni < 4; ++ni)
#pragma unroll
      for (int r = 0; r < 4; ++r) sacc[ni][r] = 0.0f;
#pragma unroll
    for (int ks = 0; ks < 2; ++ks) {
      bf16x8 aq = *(const bf16x8*)(&Qs[wave * 16 + l15][ks * 32 + quad * 8]);
#pragma unroll
      for (int ni = 0; ni < 4; ++ni) {
        bf16x8 bk = *(const bf16x8*)(&Ks[ni * 16 + l15][ks * 32 + quad * 8]);
        sacc[ni] = MFMA(aq, bk, sacc[ni]);
      }
    }
    float s_v[4][4];
#pragma unroll
    for (int ni = 0; ni < 4; ++ni)
#pragma unroll
      for (int r = 0; r < 4; ++r) {
        float sv = sacc[ni][r] * 0.125f;  // DH^-0.5
        if (k0 + ni * 16 + l15 >= Sk) sv = -1e30f;
        s_v[ni][r] = sv;
      }
    float alpha[4];
#pragma unroll
    for (int r = 0; r < 4; ++r) {
      float v = fmaxf(fmaxf(s_v[0][r], s_v[1][r]), fmaxf(s_v[2][r], s_v[3][r]));
#pragma unroll
      for (int off = 1; off < 16; off <<= 1) v = fmaxf(v, __shfl_xor(v, off));
      float mn = fmaxf(m_r[r], v);
      alpha[r] = __expf(m_r[r] - mn);
      m_r[r] = mn;
    }
    float p_v[4][4];
#pragma unroll
    for (int ni = 0; ni < 4; ++ni)
#pragma unroll
      for (int r = 0; r < 4; ++r) p_v[ni][r] = __expf(s_v[ni][r] - m_r[r]);
#pragma unroll
    for (int r = 0; r < 4; ++r) {
      float v = p_v[0][r] + p_v[1][r] + p_v[2][r] + p_v[3][r];
#pragma unroll
      for (int off = 1; off < 16; off <<= 1) v += __shfl_xor(v, off);
      l_r[r] = l_r[r] * alpha[r] + v;
    }
#pragma unroll
    for (int ni = 0; ni < 4; ++ni)
#pragma unroll
      for (int r = 0; r < 4; ++r) acc_o[ni][r] *= alpha[r];
    // P: C-layout -> A-layout via per-wave LDS strip (wave-private; lgkmcnt handles RAW)
#pragma unroll
    for (int ni = 0; ni < 4; ++ni)
#pragma unroll
      for (int r = 0; r < 4; ++r)
        Ps[wave][quad * 4 + r][ni * 16 + l15] = (bf16)p_v[ni][r];
#pragma unroll
    for (int ks = 0; ks < 2; ++ks) {
      bf16x8 ap = *(const bf16x8*)(&Ps[wave][l15][ks * 32 + quad * 8]);
#pragma unroll
      for (int ni = 0; ni < 4; ++ni) {
        bf16x8 bv = *(const bf16x8*)(&Vt[ni * 16 + l15][ks * 32 + quad * 8]);
        acc_o[ni] = MFMA(ap, bv, acc_o[ni]);
      }
    }
    __syncthreads();
  }
#pragma unroll
  for (int ni = 0; ni < 4; ++ni)
#pragma unroll
    for (int r = 0; r < 4; ++r) {
      int q = qt * 64 + wave * 16 + quad * 4 + r;
      float ov = acc_o[ni][r] / l_r[r];
      O[(size_t)(b * Sq + q) * 1024 + h * 64 + ni * 16 + l15] = (bf16)ov;
    }
}

extern "C" void kernel_launch(void* const* d_in, const int* in_sizes, int n_in,
                              void* d_out, int out_size, void* d_ws, size_t ws_size,
                              hipStream_t stream) {
  (void)in_sizes; (void)n_in; (void)out_size; (void)ws_size;
  const float* x = (const float*)d_in[0];
  const float* ctx = (const float*)d_in[1];
  const float* ln1_g = (const float*)d_in[2];
  const float* ln1_b = (const float*)d_in[3];
  const float* ln2_g = (const float*)d_in[4];
  const float* ln2_b = (const float*)d_in[5];
  const float* ln3_g = (const float*)d_in[6];
  const float* ln3_b = (const float*)d_in[7];
  const float* a1_wq = (const float*)d_in[8];
  const float* a1_wk = (const float*)d_in[9];
  const float* a1_wv = (const float*)d_in[10];
  const float* a1_wo = (const float*)d_in[11];
  const float* a1_bo = (const float*)d_in[12];
  const float* a2_wq = (const float*)d_in[13];
  const float* a2_wk = (const float*)d_in[14];
  const float* a2_wv = (const float*)d_in[15];
  const float* a2_wo = (const float*)d_in[16];
  const float* a2_bo = (const float*)d_in[17];
  const float* ff_w1 = (const float*)d_in[18];
  const float* ff_b1 = (const float*)d_in[19];
  const float* ff_w2 = (const float*)d_in[20];
  const float* ff_b2 = (const float*)d_in[21];
  float* xout = (float*)d_out;

  const int M = 4 * 2048;  // 8192 rows
  char* ws = (char*)d_ws;
  size_t off = 0;
  auto alloc = [&](size_t elems) -> bf16* {
    bf16* p = (bf16*)(ws + off);
    off += ((elems * sizeof(bf16)) + 255) & ~(size_t)255;
    return p;
  };
  bf16* wq1t = alloc((size_t)1024 * 1024);
  bf16* wk1t = alloc((size_t)1024 * 1024);
  bf16* wv1t = alloc((size_t)1024 * 1024);
  bf16* wo1t = alloc((size_t)1024 * 1024);
  bf16* wq2t = alloc((size_t)1024 * 1024);
  bf16* wk2t = alloc((size_t)1024 * 768);
  bf16* wv2t = alloc((size_t)1024 * 768);
  bf16* wo2t = alloc((size_t)1024 * 1024);
  bf16* w1t = alloc((size_t)8192 * 1024);
  bf16* w2t = alloc((size_t)1024 * 4096);
  bf16* lnb = alloc((size_t)M * 1024);
  bf16* qb = alloc((size_t)M * 1024);
  bf16* kb = alloc((size_t)M * 1024);
  bf16* vb = alloc((size_t)M * 1024);
  bf16* ab = alloc((size_t)M * 1024);
  bf16* ctxb = alloc((size_t)308 * 768);
  bf16* kcb = alloc((size_t)308 * 1024);
  bf16* vcb = alloc((size_t)308 * 1024);
  bf16* hgb = alloc((size_t)M * 4096);

  // running residual x lives in d_out (fp32)
  hipMemcpyAsync(xout, x, (size_t)M * 1024 * sizeof(float),
                 hipMemcpyDeviceToDevice, stream);

  // weights -> bf16 transposed (N x K)
  k_transpose_cvt<<<dim3(32, 32), 256, 0, stream>>>(a1_wq, wq1t, 1024, 1024);
  k_transpose_cvt<<<dim3(32, 32), 256, 0, stream>>>(a1_wk, wk1t, 1024, 1024);
  k_transpose_cvt<<<dim3(32, 32), 256, 0, stream>>>(a1_wv, wv1t, 1024, 1024);
  k_transpose_cvt<<<dim3(32, 32), 256, 0, stream>>>(a1_wo, wo1t, 1024, 1024);
  k_transpose_cvt<<<dim3(32, 32), 256, 0, stream>>>(a2_wq, wq2t, 1024, 1024);
  k_transpose_cvt<<<dim3(24, 32), 256, 0, stream>>>(a2_wk, wk2t, 768, 1024);
  k_transpose_cvt<<<dim3(24, 32), 256, 0, stream>>>(a2_wv, wv2t, 768, 1024);
  k_transpose_cvt<<<dim3(32, 32), 256, 0, stream>>>(a2_wo, wo2t, 1024, 1024);
  k_transpose_cvt<<<dim3(32, 256), 256, 0, stream>>>(ff_w1, w1t, 1024, 8192);
  k_transpose_cvt<<<dim3(128, 32), 256, 0, stream>>>(ff_w2, w2t, 4096, 1024);
  k_cvt<<<(308 * 768 + 255) / 256, 256, 0, stream>>>(ctx, ctxb, 308 * 768);

  // ---- self-attention ----
  k_layernorm<<<M, 256, 0, stream>>>(xout, ln1_g, ln1_b, lnb);
  k_gemm_bt<0><<<dim3(64, 8), 256, 0, stream>>>(lnb, wq1t, nullptr, nullptr, qb, M, 1024, 1024);
  k_gemm_bt<0><<<dim3(64, 8), 256, 0, stream>>>(lnb, wk1t, nullptr, nullptr, kb, M, 1024, 1024);
  k_gemm_bt<0><<<dim3(64, 8), 256, 0, stream>>>(lnb, wv1t, nullptr, nullptr, vb, M, 1024, 1024);
  k_flash<<<dim3(32, 16, 4), 256, 0, stream>>>(qb, kb, vb, ab, 2048, 2048, 2048);
  k_gemm_bt<1><<<dim3(64, 8), 256, 0, stream>>>(ab, wo1t, a1_bo, xout, xout, M, 1024, 1024);

  // ---- cross-attention ----
  k_layernorm<<<M, 256, 0, stream>>>(xout, ln2_g, ln2_b, lnb);
  k_gemm_bt<0><<<dim3(64, 8), 256, 0, stream>>>(lnb, wq2t, nullptr, nullptr, qb, M, 1024, 1024);
  k_gemm_bt<0><<<dim3(3, 8), 256, 0, stream>>>(ctxb, wk2t, nullptr, nullptr, kcb, 308, 1024, 768);
  k_gemm_bt<0><<<dim3(3, 8), 256, 0, stream>>>(ctxb, wv2t, nullptr, nullptr, vcb, 308, 1024, 768);
  k_flash<<<dim3(32, 16, 4), 256, 0, stream>>>(qb, kcb, vcb, ab, 2048, 77, 77);
  k_gemm_bt<1><<<dim3(64, 8), 256, 0, stream>>>(ab, wo2t, a2_bo, xout, xout, M, 1024, 1024);

  // ---- GeGLU feed-forward ----
  k_layernorm<<<M, 256, 0, stream>>>(xout, ln3_g, ln3_b, lnb);
  k_gemm_geglu<<<dim3(64, 64), 256, 0, stream>>>(lnb, w1t, ff_b1, hgb, M, 1024);
  k_gemm_bt<1><<<dim3(64, 8), 256, 0, stream>>>(hgb, w2t, ff_b2, xout, xout, M, 1024, 4096);
}

// Round 4
// 923.839 us; speedup vs baseline: 2.5050x; 1.0717x over previous
//
#include <hip/hip_runtime.h>
#include <hip/hip_bf16.h>
#include <math.h>

typedef __bf16 bf16;
typedef __bf16 bf16x8 __attribute__((ext_vector_type(8)));
typedef float f32x4 __attribute__((ext_vector_type(4)));

#define MFMA(a, b, c) __builtin_amdgcn_mfma_f32_16x16x32_bf16((a), (b), (c), 0, 0, 0)

// async global->LDS, 16B per lane. LDS dest must be wave-uniform base + lane*16.
static __device__ __forceinline__ void gl16(const bf16* g, bf16* l) {
  __builtin_amdgcn_global_load_lds(
      (const __attribute__((address_space(1))) void*)g,
      (__attribute__((address_space(3))) void*)l, 16, 0, 0);
}

static __device__ __forceinline__ bf16x8 bzero8() {
  bf16x8 v;
#pragma unroll
  for (int i = 0; i < 8; ++i) v[i] = (bf16)0.0f;
  return v;
}

// ---------- W (K x N fp32, row-major) -> Wt (N x K bf16, row-major) ----------
__global__ void k_transpose_cvt(const float* __restrict__ W, bf16* __restrict__ Wt,
                                int K, int N) {
  __shared__ float tile[32][33];
  int k0 = blockIdx.x * 32, n0 = blockIdx.y * 32;
  int tx = threadIdx.x & 31, ty = threadIdx.x >> 5;
  for (int i = ty; i < 32; i += 8)
    tile[i][tx] = W[(size_t)(k0 + i) * N + (n0 + tx)];
  __syncthreads();
  for (int i = ty; i < 32; i += 8)
    Wt[(size_t)(n0 + i) * K + (k0 + tx)] = (bf16)tile[tx][i];
}

// ---------- V (rows x 1024 bf16, token-major) -> Vt[b][h][d][kvpad] ----------
__global__ void k_transpose_v(const bf16* __restrict__ V, bf16* __restrict__ Vt,
                              int rows, int kvpad) {
  __shared__ __attribute__((aligned(16))) bf16 tile[64][72];
  int t0 = blockIdx.x * 64, h = blockIdx.y, b = blockIdx.z;
  int t = threadIdx.x;
  int tr = t >> 2, c0 = (t & 3) * 16;
  int token = t0 + tr;
  bf16x8 a = bzero8(), bv = bzero8();
  if (token < rows) {
    const bf16* src = V + ((size_t)(b * rows + token)) * 1024 + h * 64 + c0;
    a = *(const bf16x8*)src;
    bv = *(const bf16x8*)(src + 8);
  }
  *(bf16x8*)&tile[tr][c0] = a;
  *(bf16x8*)&tile[tr][c0 + 8] = bv;
  __syncthreads();
  int d = t >> 2, tq = (t & 3) * 16;
  bf16x8 o1, o2;
#pragma unroll
  for (int i = 0; i < 8; ++i) { o1[i] = tile[tq + i][d]; o2[i] = tile[tq + 8 + i][d]; }
  bf16* dst = Vt + ((size_t)((b * 16 + h) * 64 + d)) * kvpad + t0 + tq;
  *(bf16x8*)dst = o1;
  *(bf16x8*)(dst + 8) = o2;
}

// ---------- fp32 -> bf16 flat convert ----------
__global__ void k_cvt(const float* __restrict__ in, bf16* __restrict__ out, int n) {
  int i = blockIdx.x * 256 + threadIdx.x;
  if (i < n) out[i] = (bf16)in[i];
}

// ---------- LayerNorm over D=1024, one block per row, bf16 out ----------
__global__ void k_layernorm(const float* __restrict__ x, const float* __restrict__ g,
                            const float* __restrict__ b, bf16* __restrict__ out) {
  int row = blockIdx.x;
  float4 v = ((const float4*)(x + (size_t)row * 1024))[threadIdx.x];
  float s = v.x + v.y + v.z + v.w;
  float ss = v.x * v.x + v.y * v.y + v.z * v.z + v.w * v.w;
#pragma unroll
  for (int off = 1; off < 64; off <<= 1) {
    s += __shfl_xor(s, off);
    ss += __shfl_xor(ss, off);
  }
  __shared__ float sm[4], sm2[4];
  int w = threadIdx.x >> 6;
  if ((threadIdx.x & 63) == 0) { sm[w] = s; sm2[w] = ss; }
  __syncthreads();
  s = sm[0] + sm[1] + sm[2] + sm[3];
  ss = sm2[0] + sm2[1] + sm2[2] + sm2[3];
  float mu = s * (1.0f / 1024.0f);
  float var = ss * (1.0f / 1024.0f) - mu * mu;
  float rs = rsqrtf(var + 1e-5f);
  float4 gg = ((const float4*)g)[threadIdx.x];
  float4 bb = ((const float4*)b)[threadIdx.x];
  bf16* o = out + (size_t)row * 1024 + threadIdx.x * 4;
  o[0] = (bf16)((v.x - mu) * rs * gg.x + bb.x);
  o[1] = (bf16)((v.y - mu) * rs * gg.y + bb.y);
  o[2] = (bf16)((v.z - mu) * rs * gg.z + bb.z);
  o[3] = (bf16)((v.w - mu) * rs * gg.w + bb.w);
}

// ---------- GEMM: C[M,N] = A[M,K] @ Bt[N,K]^T  (bf16 in, fp32 acc) ----------
template <int EPI>
__global__ __launch_bounds__(256, 2)
void k_gemm_bt(const bf16* __restrict__ A, const bf16* __restrict__ Bt,
               const float* __restrict__ bias, const float* __restrict__ res,
               void* __restrict__ Cp, int M, int N, int K) {
  __shared__ __attribute__((aligned(16))) bf16 As[128 * 32];
  __shared__ __attribute__((aligned(16))) bf16 Bs[128 * 32];
  int m0 = blockIdx.x * 128, n0 = blockIdx.y * 128;
  int tid = threadIdx.x, lane = tid & 63, wave = tid >> 6;
  int wm = (wave >> 1) * 64, wn = (wave & 1) * 64;
  int quad = lane >> 4, l15 = lane & 15;
  f32x4 acc[4][4];
#pragma unroll
  for (int i = 0; i < 4; ++i)
#pragma unroll
    for (int j = 0; j < 4; ++j)
#pragma unroll
      for (int r = 0; r < 4; ++r) acc[i][j][r] = 0.0f;
  int srow = wave * 16 + (lane >> 2), scol = (lane & 3) * 8;
  const bf16* ga = A + (size_t)(m0 + srow) * K + scol;
  const bf16* gb = Bt + (size_t)(n0 + srow) * K + scol;
  bf16* la = As + srow * 32 + scol;
  bf16* lb = Bs + srow * 32 + scol;
  for (int k0 = 0; k0 < K; k0 += 32) {
    gl16(ga, la);
    gl16(ga + (size_t)64 * K, la + 64 * 32);
    gl16(gb, lb);
    gl16(gb + (size_t)64 * K, lb + 64 * 32);
    ga += 32; gb += 32;
    __syncthreads();
    bf16x8 af[4], bfr[4];
#pragma unroll
    for (int i = 0; i < 4; ++i) af[i] = *(const bf16x8*)(&As[(wm + i * 16 + l15) * 32 + quad * 8]);
#pragma unroll
    for (int i = 0; i < 4; ++i) bfr[i] = *(const bf16x8*)(&Bs[(wn + i * 16 + l15) * 32 + quad * 8]);
#pragma unroll
    for (int mi = 0; mi < 4; ++mi)
#pragma unroll
      for (int ni = 0; ni < 4; ++ni)
        acc[mi][ni] = MFMA(af[mi], bfr[ni], acc[mi][ni]);
    __syncthreads();
  }
#pragma unroll
  for (int mi = 0; mi < 4; ++mi) {
#pragma unroll
    for (int r = 0; r < 4; ++r) {
      int row = m0 + wm + mi * 16 + quad * 4 + r;
      if (row >= M) continue;
#pragma unroll
      for (int ni = 0; ni < 4; ++ni) {
        int col = n0 + wn + ni * 16 + l15;
        float v = acc[mi][ni][r];
        if (EPI == 0) {
          ((bf16*)Cp)[(size_t)row * N + col] = (bf16)v;
        } else {
          ((float*)Cp)[(size_t)row * N + col] =
              v + bias[col] + res[(size_t)row * N + col];
        }
      }
    }
  }
}

// ---------- GEMM + GeGLU, 128x128 tile, dual accumulators ----------
__global__ __launch_bounds__(256, 2)
void k_gemm_geglu(const bf16* __restrict__ A, const bf16* __restrict__ W1t,
                  const float* __restrict__ b1, bf16* __restrict__ Hg,
                  int M, int K) {
  __shared__ __attribute__((aligned(16))) bf16 As[128 * 32];
  __shared__ __attribute__((aligned(16))) bf16 Bu[128 * 32];
  __shared__ __attribute__((aligned(16))) bf16 Bg[128 * 32];
  const int N = 4096;
  int m0 = blockIdx.x * 128, n0 = blockIdx.y * 128;
  int tid = threadIdx.x, lane = tid & 63, wave = tid >> 6;
  int wm = (wave >> 1) * 64, wn = (wave & 1) * 64;
  int quad = lane >> 4, l15 = lane & 15;
  f32x4 accu[4][4], accg[4][4];
#pragma unroll
  for (int i = 0; i < 4; ++i)
#pragma unroll
    for (int j = 0; j < 4; ++j)
#pragma unroll
      for (int r = 0; r < 4; ++r) { accu[i][j][r] = 0.0f; accg[i][j][r] = 0.0f; }
  int srow = wave * 16 + (lane >> 2), scol = (lane & 3) * 8;
  const bf16* ga = A + (size_t)(m0 + srow) * K + scol;
  const bf16* gu = W1t + (size_t)(n0 + srow) * K + scol;
  const bf16* gg = W1t + (size_t)(n0 + srow + 4096) * K + scol;
  bf16* la = As + srow * 32 + scol;
  bf16* lu = Bu + srow * 32 + scol;
  bf16* lg = Bg + srow * 32 + scol;
  for (int k0 = 0; k0 < K; k0 += 32) {
    gl16(ga, la);
    gl16(ga + (size_t)64 * K, la + 64 * 32);
    gl16(gu, lu);
    gl16(gu + (size_t)64 * K, lu + 64 * 32);
    gl16(gg, lg);
    gl16(gg + (size_t)64 * K, lg + 64 * 32);
    ga += 32; gu += 32; gg += 32;
    __syncthreads();
    bf16x8 af[4], bu[4], bg[4];
#pragma unroll
    for (int i = 0; i < 4; ++i) af[i] = *(const bf16x8*)(&As[(wm + i * 16 + l15) * 32 + quad * 8]);
#pragma unroll
    for (int i = 0; i < 4; ++i) bu[i] = *(const bf16x8*)(&Bu[(wn + i * 16 + l15) * 32 + quad * 8]);
#pragma unroll
    for (int i = 0; i < 4; ++i) bg[i] = *(const bf16x8*)(&Bg[(wn + i * 16 + l15) * 32 + quad * 8]);
#pragma unroll
    for (int mi = 0; mi < 4; ++mi)
#pragma unroll
      for (int ni = 0; ni < 4; ++ni) {
        accu[mi][ni] = MFMA(af[mi], bu[ni], accu[mi][ni]);
        accg[mi][ni] = MFMA(af[mi], bg[ni], accg[mi][ni]);
      }
    __syncthreads();
  }
#pragma unroll
  for (int mi = 0; mi < 4; ++mi)
#pragma unroll
    for (int r = 0; r < 4; ++r) {
      int row = m0 + wm + mi * 16 + quad * 4 + r;
#pragma unroll
      for (int ni = 0; ni < 4; ++ni) {
        int col = n0 + wn + ni * 16 + l15;
        float u = accu[mi][ni][r] + b1[col];
        float g = accg[mi][ni][r] + b1[col + 4096];
        float ge = 0.5f * g * (1.0f + erff(g * 0.70710678118654752f));
        Hg[(size_t)row * N + col] = (bf16)(u * ge);
      }
    }
}

// ---------- Flash attention: 64 q-rows/block, 64-key chunks, pre-transposed V --
// Q,K: token-major (*,1024), head h at col h*64. VtG: [b][h][64][kvpad].
__global__ __launch_bounds__(256, 2)
void k_flash(const bf16* __restrict__ Q, const bf16* __restrict__ Kb,
             const bf16* __restrict__ VtG, bf16* __restrict__ O,
             int Sq, int Sk, int kvrows, int kvpad) {
  __shared__ __attribute__((aligned(16))) bf16 Ks[64][72];
  __shared__ __attribute__((aligned(16))) bf16 Vs[64][72];  // Vs[d][key]
  __shared__ __attribute__((aligned(16))) bf16 Ps[4][16][72];
  int qt = blockIdx.x, h = blockIdx.y, b = blockIdx.z;
  int tid = threadIdx.x, lane = tid & 63, wave = tid >> 6;
  int quad = lane >> 4, l15 = lane & 15;
  // Q fragments resident in registers (loop-invariant)
  const bf16* qsrc = Q + (size_t)(b * Sq + qt * 64 + wave * 16 + l15) * 1024 + h * 64 + quad * 8;
  bf16x8 aq0 = *(const bf16x8*)qsrc;
  bf16x8 aq1 = *(const bf16x8*)(qsrc + 32);
  bf16x8 ones8;
#pragma unroll
  for (int i = 0; i < 8; ++i) ones8[i] = (bf16)1.0f;

  float m_r[4], l_r[4];
  f32x4 acc_o[4];
#pragma unroll
  for (int r = 0; r < 4; ++r) { m_r[r] = -1e30f; l_r[r] = 0.0f; }
#pragma unroll
  for (int ni = 0; ni < 4; ++ni)
#pragma unroll
    for (int r = 0; r < 4; ++r) acc_o[ni][r] = 0.0f;

  int tr = tid >> 2, c0 = (tid & 3) * 16;
  const bf16* vrow = VtG + ((size_t)((b * 16 + h) * 64 + tr)) * kvpad + c0;

  for (int k0 = 0; k0 < Sk; k0 += 64) {
    {
      int krow = k0 + tr;
      bf16x8 k1 = bzero8(), k2 = bzero8();
      if (krow < Sk) {
        const bf16* ks = Kb + (size_t)(b * kvrows + krow) * 1024 + h * 64 + c0;
        k1 = *(const bf16x8*)ks;
        k2 = *(const bf16x8*)(ks + 8);
      }
      *(bf16x8*)(&Ks[tr][c0]) = k1;
      *(bf16x8*)(&Ks[tr][c0 + 8]) = k2;
      // V rows (d-major): contiguous keys, no transpose needed
      bf16x8 v1 = *(const bf16x8*)(vrow + k0);
      bf16x8 v2 = *(const bf16x8*)(vrow + k0 + 8);
      *(bf16x8*)(&Vs[tr][c0]) = v1;
      *(bf16x8*)(&Vs[tr][c0 + 8]) = v2;
    }
    __syncthreads();

    // S = Q @ K^T -> sacc[ni][r] = S[quad*4+r][ni*16+l15]
    f32x4 sacc[4];
#pragma unroll
    for (int ni = 0; ni < 4; ++ni)
#pragma unroll
      for (int r = 0; r < 4; ++r) sacc[ni][r] = 0.0f;
#pragma unroll
    for (int ni = 0; ni < 4; ++ni) {
      bf16x8 bk0 = *(const bf16x8*)(&Ks[ni * 16 + l15][quad * 8]);
      bf16x8 bk1 = *(const bf16x8*)(&Ks[ni * 16 + l15][32 + quad * 8]);
      sacc[ni] = MFMA(aq0, bk0, sacc[ni]);
      sacc[ni] = MFMA(aq1, bk1, sacc[ni]);
    }
    float s_v[4][4];
#pragma unroll
    for (int ni = 0; ni < 4; ++ni)
#pragma unroll
      for (int r = 0; r < 4; ++r) {
        float sv = sacc[ni][r] * 0.125f;  // DH^-0.5
        if (k0 + ni * 16 + l15 >= Sk) sv = -1e30f;
        s_v[ni][r] = sv;
      }
    float alpha[4];
#pragma unroll
    for (int r = 0; r < 4; ++r) {
      float v = fmaxf(fmaxf(s_v[0][r], s_v[1][r]), fmaxf(s_v[2][r], s_v[3][r]));
#pragma unroll
      for (int off = 1; off < 16; off <<= 1) v = fmaxf(v, __shfl_xor(v, off));
      float mn = fmaxf(m_r[r], v);
      alpha[r] = __expf(m_r[r] - mn);
      m_r[r] = mn;
    }
    // P + C->A layout round trip through wave-private LDS strip
#pragma unroll
    for (int ni = 0; ni < 4; ++ni)
#pragma unroll
      for (int r = 0; r < 4; ++r)
        Ps[wave][quad * 4 + r][ni * 16 + l15] = (bf16)__expf(s_v[ni][r] - m_r[r]);
    bf16x8 ap0 = *(const bf16x8*)(&Ps[wave][l15][quad * 8]);
    bf16x8 ap1 = *(const bf16x8*)(&Ps[wave][l15][32 + quad * 8]);
    // row-sum of P via MFMA with ones (replaces shuffle-reduce)
    f32x4 psum;
#pragma unroll
    for (int r = 0; r < 4; ++r) psum[r] = 0.0f;
    psum = MFMA(ap0, ones8, psum);
    psum = MFMA(ap1, ones8, psum);
#pragma unroll
    for (int r = 0; r < 4; ++r) l_r[r] = l_r[r] * alpha[r] + psum[r];
#pragma unroll
    for (int ni = 0; ni < 4; ++ni) {
#pragma unroll
      for (int r = 0; r < 4; ++r) acc_o[ni][r] *= alpha[r];
      bf16x8 bv0 = *(const bf16x8*)(&Vs[ni * 16 + l15][quad * 8]);
      bf16x8 bv1 = *(const bf16x8*)(&Vs[ni * 16 + l15][32 + quad * 8]);
      acc_o[ni] = MFMA(ap0, bv0, acc_o[ni]);
      acc_o[ni] = MFMA(ap1, bv1, acc_o[ni]);
    }
    __syncthreads();
  }
#pragma unroll
  for (int ni = 0; ni < 4; ++ni)
#pragma unroll
    for (int r = 0; r < 4; ++r) {
      int q = qt * 64 + wave * 16 + quad * 4 + r;
      float ov = acc_o[ni][r] / l_r[r];
      O[(size_t)(b * Sq + q) * 1024 + h * 64 + ni * 16 + l15] = (bf16)ov;
    }
}

extern "C" void kernel_launch(void* const* d_in, const int* in_sizes, int n_in,
                              void* d_out, int out_size, void* d_ws, size_t ws_size,
                              hipStream_t stream) {
  (void)in_sizes; (void)n_in; (void)out_size; (void)ws_size;
  const float* x = (const float*)d_in[0];
  const float* ctx = (const float*)d_in[1];
  const float* ln1_g = (const float*)d_in[2];
  const float* ln1_b = (const float*)d_in[3];
  const float* ln2_g = (const float*)d_in[4];
  const float* ln2_b = (const float*)d_in[5];
  const float* ln3_g = (const float*)d_in[6];
  const float* ln3_b = (const float*)d_in[7];
  const float* a1_wq = (const float*)d_in[8];
  const float* a1_wk = (const float*)d_in[9];
  const float* a1_wv = (const float*)d_in[10];
  const float* a1_wo = (const float*)d_in[11];
  const float* a1_bo = (const float*)d_in[12];
  const float* a2_wq = (const float*)d_in[13];
  const float* a2_wk = (const float*)d_in[14];
  const float* a2_wv = (const float*)d_in[15];
  const float* a2_wo = (const float*)d_in[16];
  const float* a2_bo = (const float*)d_in[17];
  const float* ff_w1 = (const float*)d_in[18];
  const float* ff_b1 = (const float*)d_in[19];
  const float* ff_w2 = (const float*)d_in[20];
  const float* ff_b2 = (const float*)d_in[21];
  float* xout = (float*)d_out;

  const int M = 4 * 2048;  // 8192 rows
  char* ws = (char*)d_ws;
  size_t off = 0;
  auto alloc = [&](size_t elems) -> bf16* {
    bf16* p = (bf16*)(ws + off);
    off += ((elems * sizeof(bf16)) + 255) & ~(size_t)255;
    return p;
  };
  bf16* wq1t = alloc((size_t)1024 * 1024);
  bf16* wk1t = alloc((size_t)1024 * 1024);
  bf16* wv1t = alloc((size_t)1024 * 1024);
  bf16* wo1t = alloc((size_t)1024 * 1024);
  bf16* wq2t = alloc((size_t)1024 * 1024);
  bf16* wk2t = alloc((size_t)1024 * 768);
  bf16* wv2t = alloc((size_t)1024 * 768);
  bf16* wo2t = alloc((size_t)1024 * 1024);
  bf16* w1t = alloc((size_t)8192 * 1024);
  bf16* w2t = alloc((size_t)1024 * 4096);
  bf16* lnb = alloc((size_t)M * 1024);
  bf16* qb = alloc((size_t)M * 1024);
  bf16* kb = alloc((size_t)M * 1024);
  bf16* vb = alloc((size_t)M * 1024);
  bf16* ab = alloc((size_t)M * 1024);
  bf16* ctxb = alloc((size_t)308 * 768);
  bf16* kcb = alloc((size_t)308 * 1024);
  bf16* vcb = alloc((size_t)308 * 1024);
  bf16* hgb = alloc((size_t)M * 4096);
  // Vt buffers alias hgb (attention phases finish before geglu writes hgb)
  bf16* vtb = hgb;                                   // 4*16*64*2048 = 8.4M elems
  bf16* vtcb = hgb + (size_t)4 * 16 * 64 * 2048;     // 4*16*64*128

  // running residual x lives in d_out (fp32)
  hipMemcpyAsync(xout, x, (size_t)M * 1024 * sizeof(float),
                 hipMemcpyDeviceToDevice, stream);

  // weights -> bf16 transposed (N x K)
  k_transpose_cvt<<<dim3(32, 32), 256, 0, stream>>>(a1_wq, wq1t, 1024, 1024);
  k_transpose_cvt<<<dim3(32, 32), 256, 0, stream>>>(a1_wk, wk1t, 1024, 1024);
  k_transpose_cvt<<<dim3(32, 32), 256, 0, stream>>>(a1_wv, wv1t, 1024, 1024);
  k_transpose_cvt<<<dim3(32, 32), 256, 0, stream>>>(a1_wo, wo1t, 1024, 1024);
  k_transpose_cvt<<<dim3(32, 32), 256, 0, stream>>>(a2_wq, wq2t, 1024, 1024);
  k_transpose_cvt<<<dim3(24, 32), 256, 0, stream>>>(a2_wk, wk2t, 768, 1024);
  k_transpose_cvt<<<dim3(24, 32), 256, 0, stream>>>(a2_wv, wv2t, 768, 1024);
  k_transpose_cvt<<<dim3(32, 32), 256, 0, stream>>>(a2_wo, wo2t, 1024, 1024);
  k_transpose_cvt<<<dim3(32, 256), 256, 0, stream>>>(ff_w1, w1t, 1024, 8192);
  k_transpose_cvt<<<dim3(128, 32), 256, 0, stream>>>(ff_w2, w2t, 4096, 1024);
  k_cvt<<<(308 * 768 + 255) / 256, 256, 0, stream>>>(ctx, ctxb, 308 * 768);

  // ---- self-attention ----
  k_layernorm<<<M, 256, 0, stream>>>(xout, ln1_g, ln1_b, lnb);
  k_gemm_bt<0><<<dim3(64, 8), 256, 0, stream>>>(lnb, wq1t, nullptr, nullptr, qb, M, 1024, 1024);
  k_gemm_bt<0><<<dim3(64, 8), 256, 0, stream>>>(lnb, wk1t, nullptr, nullptr, kb, M, 1024, 1024);
  k_gemm_bt<0><<<dim3(64, 8), 256, 0, stream>>>(lnb, wv1t, nullptr, nullptr, vb, M, 1024, 1024);
  k_transpose_v<<<dim3(32, 16, 4), 256, 0, stream>>>(vb, vtb, 2048, 2048);
  k_flash<<<dim3(32, 16, 4), 256, 0, stream>>>(qb, kb, vtb, ab, 2048, 2048, 2048, 2048);
  k_gemm_bt<1><<<dim3(64, 8), 256, 0, stream>>>(ab, wo1t, a1_bo, xout, xout, M, 1024, 1024);

  // ---- cross-attention ----
  k_layernorm<<<M, 256, 0, stream>>>(xout, ln2_g, ln2_b, lnb);
  k_gemm_bt<0><<<dim3(64, 8), 256, 0, stream>>>(lnb, wq2t, nullptr, nullptr, qb, M, 1024, 1024);
  k_gemm_bt<0><<<dim3(3, 8), 256, 0, stream>>>(ctxb, wk2t, nullptr, nullptr, kcb, 308, 1024, 768);
  k_gemm_bt<0><<<dim3(3, 8), 256, 0, stream>>>(ctxb, wv2t, nullptr, nullptr, vcb, 308, 1024, 768);
  k_transpose_v<<<dim3(2, 16, 4), 256, 0, stream>>>(vcb, vtcb, 77, 128);
  k_flash<<<dim3(32, 16, 4), 256, 0, stream>>>(qb, kcb, vtcb, ab, 2048, 77, 77, 128);
  k_gemm_bt<1><<<dim3(64, 8), 256, 0, stream>>>(ab, wo2t, a2_bo, xout, xout, M, 1024, 1024);

  // ---- GeGLU feed-forward ----
  k_layernorm<<<M, 256, 0, stream>>>(xout, ln3_g, ln3_b, lnb);
  k_gemm_geglu<<<dim3(64, 32), 256, 0, stream>>>(lnb, w1t, ff_b1, hgb, M, 1024);
  k_gemm_bt<1><<<dim3(64, 8), 256, 0, stream>>>(hgb, w2t, ff_b2, xout, xout, M, 1024, 4096);
}